// Round 7
// baseline (25.931 us; speedup 1.0000x reference)
//
#include <hip/hip_runtime.h>

// PCEN [1, F=1024, T=16384] fp32.
// R7: lane-parallel windowed EMA scan. S=0.5 => state decays 2^-k.
//  - lane l owns elements 4l..4l+3 of each 256-elem superblock: b128 loads
//    and stores are lane-linear (fully coalesced). No LDS, no barriers.
//  - EMA = per-lane C0..C3 (EMA-from-0) + 3-step shfl_up scan of C3 with
//    ratio 2^-4 (32-elem window, trunc err <= 2^-33) + seed fixups.
//  - superblock seed = prev superblock's S_63 exactly (2^-256 carry == 0
//    in fp32) -> all superblocks independent, one readlane each.

static constexpr int F = 1024;
static constexpr int T = 16384;
static constexpr int BLOCK = 256;
static constexpr int TILE = 4096;    // elements per block
static constexpr int WSEG = 1024;    // elements per wave (4 superblocks x 256)
static constexpr float EPS = 1e-6f;

typedef float v4f __attribute__((ext_vector_type(4)));

#if __has_builtin(__builtin_amdgcn_logf)
__device__ __forceinline__ float nlog2(float x) { return __builtin_amdgcn_logf(x); }
#else
__device__ __forceinline__ float nlog2(float x) { return log2f(x); }
#endif
#if __has_builtin(__builtin_amdgcn_exp2f)
__device__ __forceinline__ float nexp2(float x) { return __builtin_amdgcn_exp2f(x); }
#else
__device__ __forceinline__ float nexp2(float x) { return exp2f(x); }
#endif
#if __has_builtin(__builtin_amdgcn_sqrtf)
__device__ __forceinline__ float nsqrt(float x) { return __builtin_amdgcn_sqrtf(x); }
#else
__device__ __forceinline__ float nsqrt(float x) { return sqrtf(x); }
#endif

__device__ __forceinline__ float shup(float x, int d, int l) {
  float t = __shfl_up(x, d, 64);
  return (l >= d) ? t : 0.0f;
}

struct Scan { float C0, C1, C2, C3, S; };

// Per-lane EMA-from-zero over the lane's 4 elements, then cross-lane scan of
// C3 with ratio 2^-4 over an 8-lane (32-element) window.
__device__ __forceinline__ Scan ema_scan(v4f v, int l) {
  Scan r;
  r.C0 = 0.5f * v.x;
  r.C1 = 0.5f * (r.C0 + v.y);
  r.C2 = 0.5f * (r.C1 + v.z);
  r.C3 = 0.5f * (r.C2 + v.w);
  float S = r.C3;
  S = fmaf(0x1p-4f,  shup(S, 1, l), S);
  S = fmaf(0x1p-8f,  shup(S, 2, l), S);
  S = fmaf(0x1p-16f, shup(S, 4, l), S);
  r.S = S;
  return r;
}

__global__ __launch_bounds__(BLOCK, 8) void pcen_kernel(
    const float* __restrict__ data,
    const float* __restrict__ alpha_p,
    const float* __restrict__ r_p,
    const float* __restrict__ delta_p,
    float* __restrict__ out)
{
  const int tid = threadIdx.x;
  const int bid = blockIdx.x;
  const int f = bid >> 2;                // row (4 blocks per row)
  const int h = bid & 3;                 // tile in row
  const int w = tid >> 6;                // wave in block
  const int l = tid & 63;                // lane
  const size_t base = (size_t)f * T + (size_t)h * TILE + (size_t)w * WSEG;
  const v4f* __restrict__ g4 = reinterpret_cast<const v4f*>(data + base);

  // ---- lane-linear loads: superblock s, lane l -> g4[s*64 + l] ----
  v4f v0 = g4[0 * 64 + l];
  v4f v1 = g4[1 * 64 + l];
  v4f v2 = g4[2 * 64 + l];
  v4f v3 = g4[3 * 64 + l];
  v4f vp = {0.f, 0.f, 0.f, 0.f};         // previous 256 elems (seed region)
  if ((h | w) != 0) vp = g4[l - 64];

  // ---- independent scans (ILP) ----
  Scan p  = ema_scan(vp, l);
  Scan s0 = ema_scan(v0, l);
  Scan s1 = ema_scan(v1, l);
  Scan s2 = ema_scan(v2, l);
  Scan s3 = ema_scan(v3, l);

  // superblock seeds: m_255(prev sb) == S_63(prev sb) exactly in fp32
  const float seed0 = __shfl(p.S,  63, 64);  // 0 when no prev (vp = 0)
  const float seed1 = __shfl(s0.S, 63, 64);
  const float seed2 = __shfl(s1.S, 63, 64);
  const float seed3 = __shfl(s2.S, 63, 64);

  // lane seed weight 2^-4l (exact, underflow -> 0)
  const int ew = 127 - 4 * l;
  const float pw = (ew > 0) ? __int_as_float(ew << 23) : 0.0f;

  const float alpha = alpha_p[0];
  const float r     = r_p[0];
  const float delta = delta_p[0];
  const bool  rhalf = (r == 0.5f);
  const float delta_r = rhalf ? nsqrt(delta) : nexp2(r * nlog2(delta));
  const float nalpha = -alpha;

  v4f* __restrict__ o4 = reinterpret_cast<v4f*>(out + base);

  #define PCEN_ONE(XX, MM, OO)                                   \
    { float lgm = nlog2((MM) + EPS);                             \
      float inv = nexp2(nalpha * lgm);   /* (M+eps)^-alpha */    \
      float qq  = fmaf((XX), inv, delta);                        \
      OO = (rhalf ? nsqrt(qq) : nexp2(r * nlog2(qq))) - delta_r; }

  #define PCEN_SB(SC, SEED, V, SLOT)                             \
    { float sl = fmaf(pw, (SEED), shup((SC).S, 1, l));           \
      float m0 = fmaf(0x1p-1f, sl, (SC).C0);                     \
      float m1 = fmaf(0x1p-2f, sl, (SC).C1);                     \
      float m2 = fmaf(0x1p-3f, sl, (SC).C2);                     \
      float m3 = fmaf(0x1p-4f, sl, (SC).C3);                     \
      v4f o;                                                     \
      PCEN_ONE((V).x, m0, o.x);                                  \
      PCEN_ONE((V).y, m1, o.y);                                  \
      PCEN_ONE((V).z, m2, o.z);                                  \
      PCEN_ONE((V).w, m3, o.w);                                  \
      __builtin_nontemporal_store(o, o4 + (SLOT) * 64 + l); }

  PCEN_SB(s0, seed0, v0, 0)
  PCEN_SB(s1, seed1, v1, 1)
  PCEN_SB(s2, seed2, v2, 2)
  PCEN_SB(s3, seed3, v3, 3)

  #undef PCEN_SB
  #undef PCEN_ONE
}

extern "C" void kernel_launch(void* const* d_in, const int* in_sizes, int n_in,
                              void* d_out, int out_size, void* d_ws, size_t ws_size,
                              hipStream_t stream) {
  const float* data  = (const float*)d_in[0];
  const float* alpha = (const float*)d_in[1];
  const float* r     = (const float*)d_in[2];
  const float* delta = (const float*)d_in[3];
  float* out = (float*)d_out;

  const int grid = F * (T / TILE);   // 1024 * 4 = 4096 blocks
  pcen_kernel<<<dim3(grid), dim3(BLOCK), 0, stream>>>(data, alpha, r, delta, out);
}

// Round 9
// 25.758 us; speedup vs baseline: 1.0067x; 1.0067x over previous
//
#include <hip/hip_runtime.h>

// PCEN [1, F=1024, T=16384] fp32.
// R8 (resubmit; prior round died on container infra): lane-parallel windowed
// EMA scan (R7) +
//  - 2 segments per wave -> grid 2048 = exactly 8 blocks/CU, single
//    residency round (no second dispatch ramp/tail).
//  - seed load narrowed to lanes 56..63 (the 3-step shfl scan window is
//    exactly 8 lanes; lanes <56 contribute 0 -- exact, not approximate).
//  - segment B seeded from segment A's last-superblock scan (free).

static constexpr int F = 1024;
static constexpr int T = 16384;
static constexpr int BLOCK = 256;
static constexpr int WSEG = 2048;      // elements per wave (2 segs x 4 sb x 256)
static constexpr int BTILE = WSEG * 4; // 8192 elements per block (4 waves)
static constexpr float EPS = 1e-6f;

typedef float v4f __attribute__((ext_vector_type(4)));

#if __has_builtin(__builtin_amdgcn_logf)
__device__ __forceinline__ float nlog2(float x) { return __builtin_amdgcn_logf(x); }
#else
__device__ __forceinline__ float nlog2(float x) { return log2f(x); }
#endif
#if __has_builtin(__builtin_amdgcn_exp2f)
__device__ __forceinline__ float nexp2(float x) { return __builtin_amdgcn_exp2f(x); }
#else
__device__ __forceinline__ float nexp2(float x) { return exp2f(x); }
#endif
#if __has_builtin(__builtin_amdgcn_sqrtf)
__device__ __forceinline__ float nsqrt(float x) { return __builtin_amdgcn_sqrtf(x); }
#else
__device__ __forceinline__ float nsqrt(float x) { return sqrtf(x); }
#endif

__device__ __forceinline__ float shup(float x, int d, int l) {
  float t = __shfl_up(x, d, 64);
  return (l >= d) ? t : 0.0f;
}

struct Scan { float C0, C1, C2, C3, S; };

// Per-lane EMA-from-zero over 4 elements + cross-lane scan of C3 with ratio
// 2^-4 over an 8-lane (32-element) window.
__device__ __forceinline__ Scan ema_scan(v4f v, int l) {
  Scan r;
  r.C0 = 0.5f * v.x;
  r.C1 = 0.5f * (r.C0 + v.y);
  r.C2 = 0.5f * (r.C1 + v.z);
  r.C3 = 0.5f * (r.C2 + v.w);
  float S = r.C3;
  S = fmaf(0x1p-4f,  shup(S, 1, l), S);
  S = fmaf(0x1p-8f,  shup(S, 2, l), S);
  S = fmaf(0x1p-16f, shup(S, 4, l), S);
  r.S = S;
  return r;
}

__global__ __launch_bounds__(BLOCK) void pcen_kernel(
    const float* __restrict__ data,
    const float* __restrict__ alpha_p,
    const float* __restrict__ r_p,
    const float* __restrict__ delta_p,
    float* __restrict__ out)
{
  const int tid = threadIdx.x;
  const int bid = blockIdx.x;
  const int f = bid >> 1;                // row (2 blocks per row)
  const int h = bid & 1;                 // half of row
  const int w = tid >> 6;                // wave in block
  const int l = tid & 63;                // lane
  const size_t base = (size_t)f * T + (size_t)h * BTILE + (size_t)w * WSEG;
  const v4f* __restrict__ g4 = reinterpret_cast<const v4f*>(data + base);

  // scalar params first; their waitcnt hides under the data loads
  const float alpha = alpha_p[0];
  const float r     = r_p[0];
  const float delta = delta_p[0];

  // ---- lane-linear loads: segment A (sb 0..3), B (sb 4..7) ----
  v4f a0 = g4[0 * 64 + l];
  v4f a1 = g4[1 * 64 + l];
  v4f a2 = g4[2 * 64 + l];
  v4f a3 = g4[3 * 64 + l];
  v4f b0 = g4[4 * 64 + l];
  v4f b1 = g4[5 * 64 + l];
  v4f b2 = g4[6 * 64 + l];
  v4f b3 = g4[7 * 64 + l];
  // seed region: only the last 32 elements of the previous superblock can
  // reach S_63 through the 8-lane scan window -> load lanes 56..63 only.
  v4f vp = {0.f, 0.f, 0.f, 0.f};
  if (((h | w) != 0) && (l >= 56)) vp = g4[l - 64];

  // ---- scans ----
  Scan p  = ema_scan(vp, l);
  Scan s0 = ema_scan(a0, l);
  Scan s1 = ema_scan(a1, l);
  Scan s2 = ema_scan(a2, l);
  Scan s3 = ema_scan(a3, l);
  Scan u0 = ema_scan(b0, l);
  Scan u1 = ema_scan(b1, l);
  Scan u2 = ema_scan(b2, l);
  Scan u3 = ema_scan(b3, l);

  // superblock seeds: m_255(prev sb) == S_63(prev sb) exactly in fp32
  const float sdA0 = __shfl(p.S,  63, 64);
  const float sdA1 = __shfl(s0.S, 63, 64);
  const float sdA2 = __shfl(s1.S, 63, 64);
  const float sdA3 = __shfl(s2.S, 63, 64);
  const float sdB0 = __shfl(s3.S, 63, 64);   // B seeded by A's last sb
  const float sdB1 = __shfl(u0.S, 63, 64);
  const float sdB2 = __shfl(u1.S, 63, 64);
  const float sdB3 = __shfl(u2.S, 63, 64);

  // lane seed weight 2^-4l (exact, underflow -> 0)
  const int ew = 127 - 4 * l;
  const float pw = (ew > 0) ? __int_as_float(ew << 23) : 0.0f;

  const bool  rhalf = (r == 0.5f);
  const float delta_r = rhalf ? nsqrt(delta) : nexp2(r * nlog2(delta));
  const float nalpha = -alpha;

  v4f* __restrict__ o4 = reinterpret_cast<v4f*>(out + base);

  #define PCEN_ONE(XX, MM, OO)                                   \
    { float lgm = nlog2((MM) + EPS);                             \
      float inv = nexp2(nalpha * lgm);   /* (M+eps)^-alpha */    \
      float qq  = fmaf((XX), inv, delta);                        \
      OO = (rhalf ? nsqrt(qq) : nexp2(r * nlog2(qq))) - delta_r; }

  #define PCEN_SB(SC, SEED, V, SLOT)                             \
    { float sl = fmaf(pw, (SEED), shup((SC).S, 1, l));           \
      float m0 = fmaf(0x1p-1f, sl, (SC).C0);                     \
      float m1 = fmaf(0x1p-2f, sl, (SC).C1);                     \
      float m2 = fmaf(0x1p-3f, sl, (SC).C2);                     \
      float m3 = fmaf(0x1p-4f, sl, (SC).C3);                     \
      v4f o;                                                     \
      PCEN_ONE((V).x, m0, o.x);                                  \
      PCEN_ONE((V).y, m1, o.y);                                  \
      PCEN_ONE((V).z, m2, o.z);                                  \
      PCEN_ONE((V).w, m3, o.w);                                  \
      __builtin_nontemporal_store(o, o4 + (SLOT) * 64 + l); }

  PCEN_SB(s0, sdA0, a0, 0)
  PCEN_SB(s1, sdA1, a1, 1)
  PCEN_SB(s2, sdA2, a2, 2)
  PCEN_SB(s3, sdA3, a3, 3)
  PCEN_SB(u0, sdB0, b0, 4)
  PCEN_SB(u1, sdB1, b1, 5)
  PCEN_SB(u2, sdB2, b2, 6)
  PCEN_SB(u3, sdB3, b3, 7)

  #undef PCEN_SB
  #undef PCEN_ONE
}

extern "C" void kernel_launch(void* const* d_in, const int* in_sizes, int n_in,
                              void* d_out, int out_size, void* d_ws, size_t ws_size,
                              hipStream_t stream) {
  const float* data  = (const float*)d_in[0];
  const float* alpha = (const float*)d_in[1];
  const float* r     = (const float*)d_in[2];
  const float* delta = (const float*)d_in[3];
  float* out = (float*)d_out;

  const int grid = F * (T / BTILE);   // 1024 * 2 = 2048 blocks = 8/CU
  pcen_kernel<<<dim3(grid), dim3(BLOCK), 0, stream>>>(data, alpha, r, delta, out);
}